// Round 3
// baseline (119.004 us; speedup 1.0000x reference)
//
#include <hip/hip_runtime.h>
#include <math.h>

// Problem constants
#define F_ 126
#define NPG 128              // nodes per graph
#define EPG 2048             // edges per graph
#define ET 524288            // total edges
#define NEG_SLOPE 0.2f
// h layout (type-major): rows [0,32256) features, [32256,32512) users, [32512,32768) items
#define U_BASE 32256
#define I_BASE 32512

typedef short bf16x8 __attribute__((ext_vector_type(8)));
typedef float f32x4 __attribute__((ext_vector_type(4)));

__device__ __forceinline__ float bf2f(unsigned short u) {
  return __uint_as_float(((unsigned)u) << 16);
}
__device__ __forceinline__ unsigned short f2bf(float f) {
  unsigned x = __float_as_uint(f);
  unsigned r = x + 0x7fffu + ((x >> 16) & 1u);   // RNE
  return (unsigned short)(r >> 16);
}
// bank-spread swizzle on flat f32 indices: XOR bits 7:5 into 4:2 (bijective)
__device__ __forceinline__ int Fsw(int f) { return f ^ ((f & 0xE0) >> 3); }

__device__ __forceinline__ int growmap(int g, int r) {
  return (r < F_) ? g * F_ + r : ((r == F_) ? U_BASE + g : I_BASE + g);
}

// ---------------- K0: WcT[type][c][k] = sum_j W_type[k][j] * W_gat[j][c]  (bf16) ----------
__global__ void k0_wct(const float* __restrict__ Wf, const float* __restrict__ Wu,
                       const float* __restrict__ Wi, const float* __restrict__ Wg,
                       unsigned short* __restrict__ wct) {
  int type = blockIdx.x >> 8;       // 0..2
  int c = blockIdx.x & 255;
  const float* Wx = (type == 0) ? Wf : ((type == 1) ? Wu : Wi);
  __shared__ float gcol[256];
  gcol[threadIdx.x] = Wg[threadIdx.x * 256 + c];
  __syncthreads();
  int k = threadIdx.x;
  const float4* wrow = reinterpret_cast<const float4*>(Wx + k * 256);
  float acc = 0.f;
#pragma unroll 8
  for (int j = 0; j < 64; ++j) {
    float4 v = wrow[j];
    acc += v.x * gcol[4 * j] + v.y * gcol[4 * j + 1] + v.z * gcol[4 * j + 2] + v.w * gcol[4 * j + 3];
  }
  wct[((size_t)type * 256 + c) * 256 + k] = f2bf(acc);
}

// ---------------- K1: h = gathered_embedding @ Wc  (bf16 MFMA) + fused as/ad epilogue -----
// bid mapping: tile = bid&255, chalf = bid>>8 so the two chalf-blocks of a tile land on the
// same XCD (bid%8 == (bid+256)%8) -> second A-gather is an L2 hit.
__global__ __launch_bounds__(512, 4) void k1_h(
    const int* __restrict__ fid, const int* __restrict__ userid, const int* __restrict__ itemid,
    const float* __restrict__ ftab, const float* __restrict__ utab, const float* __restrict__ itab,
    const unsigned short* __restrict__ wct,
    const float* __restrict__ a_src, const float* __restrict__ a_dst,
    unsigned short* __restrict__ h, float* __restrict__ was, float* __restrict__ wad) {
  __shared__ __align__(16) unsigned short Al[128 * 128];  // 32KB, XOR-swizzled bf16
  __shared__ __align__(16) unsigned short Bl[128 * 128];  // 32KB
  __shared__ float asl[2][64], adl[2][64];

  const int bid = blockIdx.x;
  const int tile = bid & 255;     // 0..255 row tile (252 feat, 2 user, 2 item)
  const int chalf = bid >> 8;     // output column half (0/1 -> cols 0..127 / 128..255)
  const int tid = threadIdx.x;

  int type, rowbase;
  if (tile < 252)       { type = 0; rowbase = tile * 128; }
  else if (tile < 254)  { type = 1; rowbase = U_BASE + (tile - 252) * 128; }
  else                  { type = 2; rowbase = I_BASE + (tile - 254) * 128; }

  const int r = tid >> 2;   // 0..127 load row
  const int q = tid & 3;    // quarter of the row
  const float* srcrow;
  if (type == 0)      srcrow = ftab + (size_t)fid[tile * 128 + r] * 256;
  else if (type == 1) srcrow = utab + (size_t)userid[(tile - 252) * 128 + r] * 256;
  else                srcrow = itab + (size_t)itemid[(tile - 254) * 128 + r] * 256;
  const unsigned short* btrow = wct + ((size_t)type * 256 + chalf * 128 + r) * 256;

  // stage a_src/a_dst for this block's two heads
  if (tid < 128)      asl[tid >> 6][tid & 63] = a_src[chalf * 128 + tid];
  else if (tid < 256) { int u = tid - 128; adl[u >> 6][u & 63] = a_dst[chalf * 128 + u]; }

  const int lane = tid & 63;
  const int wid = tid >> 6;
  const int m0 = (wid & 3) * 32;
  const int n0 = (wid >> 2) * 64;
  const int rl = lane & 15;
  const int kg = lane >> 4;

  f32x4 acc[2][4] = {};
  char* Ab = reinterpret_cast<char*>(Al);
  char* Bb = reinterpret_cast<char*>(Bl);

  for (int kc = 0; kc < 2; ++kc) {
    // stage A chunk: f32 -> bf16, 8B stores, row-XOR swizzle
    {
      const float4* s4 = reinterpret_cast<const float4*>(srcrow + kc * 128 + q * 32);
#pragma unroll
      for (int i = 0; i < 8; ++i) {
        float4 v = s4[i];
        ushort4 b4;
        b4.x = f2bf(v.x); b4.y = f2bf(v.y); b4.z = f2bf(v.z); b4.w = f2bf(v.w);
        int kk = q * 32 + i * 4;
        int bofs = r * 256 + kk * 2;
        bofs ^= (r & 7) << 4;
        *reinterpret_cast<ushort4*>(Ab + bofs) = b4;
      }
      const uint4* bsrc = reinterpret_cast<const uint4*>(btrow + kc * 128 + q * 32);
#pragma unroll
      for (int i = 0; i < 4; ++i) {
        uint4 v = bsrc[i];
        int kk = q * 32 + i * 8;
        int bofs = r * 256 + kk * 2;
        bofs ^= (r & 7) << 4;
        *reinterpret_cast<uint4*>(Bb + bofs) = v;
      }
    }
    __syncthreads();
#pragma unroll
    for (int ks = 0; ks < 4; ++ks) {
      bf16x8 af[2], bfr[4];
#pragma unroll
      for (int mf = 0; mf < 2; ++mf) {
        int row = m0 + mf * 16 + rl;
        int bofs = row * 256 + (ks * 32 + kg * 8) * 2;
        bofs ^= (row & 7) << 4;
        af[mf] = *reinterpret_cast<const bf16x8*>(Ab + bofs);
      }
#pragma unroll
      for (int nf = 0; nf < 4; ++nf) {
        int row = n0 + nf * 16 + rl;
        int bofs = row * 256 + (ks * 32 + kg * 8) * 2;
        bofs ^= (row & 7) << 4;
        bfr[nf] = *reinterpret_cast<const bf16x8*>(Bb + bofs);
      }
#pragma unroll
      for (int mf = 0; mf < 2; ++mf)
#pragma unroll
        for (int nf = 0; nf < 4; ++nf)
          acc[mf][nf] = __builtin_amdgcn_mfma_f32_16x16x32_bf16(af[mf], bfr[nf], acc[mf][nf], 0, 0, 0);
    }
    __syncthreads();
  }

  // epilogue 1: as/ad partial dots from f32 acc (better precision than bf16 h)
  // thread's cols: chalf*128 + n0 + nf*16 + rl  -> head_local = n0>>6, within-head dim = nf*16+rl
  {
    const int head_local = wid >> 2;
    const int hd = chalf * 2 + head_local;
#pragma unroll
    for (int mf = 0; mf < 2; ++mf) {
#pragma unroll
      for (int i = 0; i < 4; ++i) {
        float ps = 0.f, pd = 0.f;
#pragma unroll
        for (int nf = 0; nf < 4; ++nf) {
          float v = acc[mf][nf][i];
          ps += v * asl[head_local][nf * 16 + rl];
          pd += v * adl[head_local][nf * 16 + rl];
        }
#pragma unroll
        for (int d2 = 1; d2 < 16; d2 <<= 1) {
          ps += __shfl_xor(ps, d2);
          pd += __shfl_xor(pd, d2);
        }
        if (rl == 0) {
          int grow = rowbase + m0 + mf * 16 + (lane >> 4) * 4 + i;
          was[grow * 4 + hd] = ps;
          wad[grow * 4 + hd] = pd;
        }
      }
    }
  }

  // epilogue 2: store C (bf16): row = (lane>>4)*4 + i, col = lane&15
#pragma unroll
  for (int mf = 0; mf < 2; ++mf) {
#pragma unroll
    for (int nf = 0; nf < 4; ++nf) {
      int col = chalf * 128 + n0 + nf * 16 + rl;
#pragma unroll
      for (int i = 0; i < 4; ++i) {
        int lr = m0 + mf * 16 + (lane >> 4) * 4 + i;
        h[(size_t)(rowbase + lr) * 256 + col] = f2bf(acc[mf][nf][i]);
      }
    }
  }
}

// ---------------- K2: per-graph GAT, atomic-free softmax + fused readout ------------------
// bid mapping: g = bid&255, nh = bid>>8 (graph-half pairing on same XCD for h-tile L2 reuse).
// Block (g,nh) owns dst nodes [nh*64, nh*64+64).
__global__ __launch_bounds__(512, 4) void k2_gat(
    const int* __restrict__ ei,
    const unsigned short* __restrict__ h,
    const float* __restrict__ was, const float* __restrict__ wad,
    const float* __restrict__ W_out, const float* __restrict__ b_out,
    float* __restrict__ out) {
  const int g = blockIdx.x & 255;
  const int nh = blockIdx.x >> 8;
  const int tid = threadIdx.x;
  const int lane = tid & 63;
  const int wid = tid >> 6;

  __shared__ __align__(16) unsigned short hh[128 * 128]; // 32KB, XOR-swizzled (row&7)<<4
  __shared__ float wcsr[2048 * 4];                       // 32KB: normalized alpha, Fsw-swizzled
  __shared__ float asx[512];                             // as[node][head], Fsw-swizzled
  __shared__ float adx[256];                             // ad[local node][head]
  __shared__ int cnt[64];
  __shared__ int off_[64];
  __shared__ int fill[64];
  __shared__ unsigned short sorted[2048];                // (s<<8)|((s&7)<<4): pre-swizzled row byte offset
  __shared__ float wout[256];

  char* Hb = reinterpret_cast<char*>(hh);

  // edges -> registers (4 per thread)
  int4 s4 = *reinterpret_cast<const int4*>(ei + g * EPG + tid * 4);
  int4 d4 = *reinterpret_cast<const int4*>(ei + ET + g * EPG + tid * 4);
  int sl[4] = { s4.x - g * NPG, s4.y - g * NPG, s4.z - g * NPG, s4.w - g * NPG };
  int dn[4] = { d4.x - g * NPG - nh * 64, d4.y - g * NPG - nh * 64,
                d4.z - g * NPG - nh * 64, d4.w - g * NPG - nh * 64 };

  if (tid < 64) cnt[tid] = 0;
  if (tid < 256) wout[tid] = W_out[tid];
  // stage as (all 128 nodes x 4 heads) and ad (this half's 64 nodes x 4 heads)
  {
    int n = tid >> 2, hd = tid & 3;
    asx[Fsw(tid)] = was[growmap(g, n) * 4 + hd];
  }
  if (tid < 256) {
    int n = nh * 64 + (tid >> 2);
    adx[tid] = wad[growmap(g, n) * 4 + (tid & 3)];
  }
  const float bo = b_out[0];
  __syncthreads();

  // histogram by dst (only this half's edges)
#pragma unroll
  for (int j = 0; j < 4; ++j)
    if ((unsigned)dn[j] < 64u) atomicAdd(&cnt[dn[j]], 1);
  __syncthreads();

  // wave0: exclusive prefix over 64 bins
  if (wid == 0) {
    int v0 = (lane < 64) ? cnt[lane] : 0;
    int p0 = v0;
    for (int d = 1; d < 64; d <<= 1) { int t = __shfl_up(p0, d); if (lane >= d) p0 += t; }
    off_[lane] = p0 - v0;
    fill[lane] = p0 - v0;
  }
  __syncthreads();

  // scatter into CSR (pre-swizzled src byte offsets)
#pragma unroll
  for (int j = 0; j < 4; ++j)
    if ((unsigned)dn[j] < 64u) {
      int p = atomicAdd(&fill[dn[j]], 1);
      sorted[p] = (unsigned short)((sl[j] << 8) | ((sl[j] & 7) << 4));
    }

  // issue hp=0 h-tile loads early (T14: hide HBM latency under softmax)
  const int row = tid >> 2, seg = tid & 3;
  const int hrow = growmap(g, row);
  const unsigned short* hbase = h + (size_t)hrow * 256 + seg * 32;
  uint4 stg[4];
#pragma unroll
  for (int i = 0; i < 4; ++i) stg[i] = reinterpret_cast<const uint4*>(hbase)[i];

  __syncthreads();  // sorted/off ready

  // ---- softmax: wave per (node, head), shuffle reductions, no atomics ----
  for (int t = 0; t < 32; ++t) {
    int pair = t * 8 + wid;
    int nl = pair >> 2, hd = pair & 3;
    if (nh * 64 + nl >= F_) continue;         // user/item dst rows unused
    int deg = cnt[nl];
    if (deg == 0) continue;
    int o = off_[nl];
    float adv = adx[nl * 4 + hd];
    if (deg <= 64) {
      bool act = lane < deg;
      int sv = act ? (int)sorted[o + lane] : 0;
      int s = sv >> 8;
      float lg = -INFINITY;
      if (act) {
        float e = asx[Fsw(s * 4 + hd)] + adv;
        lg = (e < 0.f) ? NEG_SLOPE * e : e;
      }
      float m = lg;
#pragma unroll
      for (int d = 32; d >= 1; d >>= 1) m = fmaxf(m, __shfl_xor(m, d));
      float ee = act ? __expf(lg - m) : 0.f;
      float sum = ee;
#pragma unroll
      for (int d = 32; d >= 1; d >>= 1) sum += __shfl_xor(sum, d);
      float rinv = __builtin_amdgcn_rcpf(sum + 1e-16f);
      if (act) wcsr[Fsw((o + lane) * 4 + hd)] = ee * rinv;
    } else {
      // generic chunked path (deg > 64; statistically never hit, must be correct)
      float m = -INFINITY;
      for (int e0 = 0; e0 < deg; e0 += 64) {
        int e = e0 + lane;
        float lg = -INFINITY;
        if (e < deg) {
          int s = (int)sorted[o + e] >> 8;
          float ev = asx[Fsw(s * 4 + hd)] + adv;
          lg = (ev < 0.f) ? NEG_SLOPE * ev : ev;
        }
        m = fmaxf(m, lg);
      }
#pragma unroll
      for (int d = 32; d >= 1; d >>= 1) m = fmaxf(m, __shfl_xor(m, d));
      float sum = 0.f;
      for (int e0 = 0; e0 < deg; e0 += 64) {
        int e = e0 + lane;
        if (e < deg) {
          int s = (int)sorted[o + e] >> 8;
          float ev = asx[Fsw(s * 4 + hd)] + adv;
          ev = (ev < 0.f) ? NEG_SLOPE * ev : ev;
          float ee = __expf(ev - m);
          wcsr[Fsw((o + e) * 4 + hd)] = ee;
          sum += ee;
        }
      }
#pragma unroll
      for (int d = 32; d >= 1; d >>= 1) sum += __shfl_xor(sum, d);
      float rinv = __builtin_amdgcn_rcpf(sum + 1e-16f);
      for (int e0 = 0; e0 < deg; e0 += 64) {
        int e = e0 + lane;
        if (e < deg) wcsr[Fsw((o + e) * 4 + hd)] *= rinv;
      }
    }
  }

  // write hh(hp=0)
#pragma unroll
  for (int i = 0; i < 4; ++i) {
    int bofs = (row * 256 + seg * 64 + i * 16) ^ ((row & 7) << 4);
    *reinterpret_cast<uint4*>(Hb + bofs) = stg[i];
  }
  __syncthreads();

  // issue hp=1 loads now (hidden under hp0 aggregation)
#pragma unroll
  for (int i = 0; i < 4; ++i) stg[i] = reinterpret_cast<const uint4*>(hbase + 128)[i];

  float lp[8];
#pragma unroll
  for (int j = 0; j < 8; ++j) lp[j] = 0.f;

  const int d0b = lane << 2;     // byte offset of this lane's 2 dims within a row
  const int lh = lane >> 5;

  for (int hp = 0; hp < 2; ++hp) {
    const int hph = hp * 2 + lh;
#pragma unroll
    for (int jn = 0; jn < 8; ++jn) {
      int nl = jn * 8 + wid;
      int n = nh * 64 + nl;
      if (n >= F_) continue;
      int deg = cnt[nl];
      float a0 = 0.f, a1 = 0.f;
      if (deg > 0) {
        int o = off_[nl];
        int k = 0;
        for (; k + 4 <= deg; k += 4) {
          int svA = sorted[o + k],     svB = sorted[o + k + 1];
          int svC = sorted[o + k + 2], svD = sorted[o + k + 3];
          int fb = (o + k) * 4 + hph;
          float wA = wcsr[Fsw(fb)],     wB = wcsr[Fsw(fb + 4)];
          float wC = wcsr[Fsw(fb + 8)], wD = wcsr[Fsw(fb + 12)];
          unsigned hA = *reinterpret_cast<const unsigned*>(Hb + (svA ^ d0b));
          unsigned hB = *reinterpret_cast<const unsigned*>(Hb + (svB ^ d0b));
          unsigned hC = *reinterpret_cast<const unsigned*>(Hb + (svC ^ d0b));
          unsigned hD = *reinterpret_cast<const unsigned*>(Hb + (svD ^ d0b));
          a0 += wA * __uint_as_float(hA << 16); a1 += wA * __uint_as_float(hA & 0xffff0000u);
          a0 += wB * __uint_as_float(hB << 16); a1 += wB * __uint_as_float(hB & 0xffff0000u);
          a0 += wC * __uint_as_float(hC << 16); a1 += wC * __uint_as_float(hC & 0xffff0000u);
          a0 += wD * __uint_as_float(hD << 16); a1 += wD * __uint_as_float(hD & 0xffff0000u);
        }
        for (; k < deg; ++k) {
          int svA = sorted[o + k];
          float wA = wcsr[Fsw((o + k) * 4 + hph)];
          unsigned hA = *reinterpret_cast<const unsigned*>(Hb + (svA ^ d0b));
          a0 += wA * __uint_as_float(hA << 16); a1 += wA * __uint_as_float(hA & 0xffff0000u);
        }
      }
      float h0 = (a0 > 0.f) ? a0 : expm1f(a0);   // ELU
      float h1 = (a1 > 0.f) ? a1 : expm1f(a1);
      lp[jn] += h0 * wout[hp * 128 + lane * 2] + h1 * wout[hp * 128 + lane * 2 + 1];
    }
    if (hp == 0) {
      __syncthreads();   // hp0 aggregation done reading hh
#pragma unroll
      for (int i = 0; i < 4; ++i) {
        int bofs = (row * 256 + seg * 64 + i * 16) ^ ((row & 7) << 4);
        *reinterpret_cast<uint4*>(Hb + bofs) = stg[i];
      }
      __syncthreads();
    }
  }

  // reduce readout partials and write logits
#pragma unroll
  for (int jn = 0; jn < 8; ++jn) {
    int n = nh * 64 + jn * 8 + wid;
    if (n < F_) {
      float v = lp[jn];
      for (int d = 32; d >= 1; d >>= 1) v += __shfl_xor(v, d);
      if (lane == 0) out[g * F_ + n] = v + bo;
    }
  }
}

extern "C" void kernel_launch(void* const* d_in, const int* in_sizes, int n_in,
                              void* d_out, int out_size, void* d_ws, size_t ws_size,
                              hipStream_t stream) {
  const int* fid      = (const int*)d_in[0];
  const int* userid   = (const int*)d_in[1];
  const int* itemid   = (const int*)d_in[2];
  const int* ei       = (const int*)d_in[3];
  const float* ftab   = (const float*)d_in[4];
  const float* utab   = (const float*)d_in[5];
  const float* itab   = (const float*)d_in[6];
  const float* Wf     = (const float*)d_in[7];
  const float* Wu     = (const float*)d_in[8];
  const float* Wi     = (const float*)d_in[9];
  const float* Wg     = (const float*)d_in[10];
  const float* a_src  = (const float*)d_in[11];
  const float* a_dst  = (const float*)d_in[12];
  const float* W_out  = (const float*)d_in[13];
  const float* b_out  = (const float*)d_in[14];
  float* out = (float*)d_out;

  // ws: h bf16 [32768][256] (16MB) + WcT bf16 3*[256][256] (384KB) + as/ad f32 [32768][4] (512KB each)
  unsigned short* ws_h   = (unsigned short*)d_ws;
  unsigned short* ws_wct = ws_h + (size_t)32768 * 256;
  float* ws_as = (float*)(ws_wct + (size_t)3 * 256 * 256);
  float* ws_ad = ws_as + (size_t)32768 * 4;

  hipLaunchKernelGGL(k0_wct, dim3(768), dim3(256), 0, stream, Wf, Wu, Wi, Wg, ws_wct);
  hipLaunchKernelGGL(k1_h, dim3(512), dim3(512), 0, stream,
                     fid, userid, itemid, ftab, utab, itab, ws_wct, a_src, a_dst,
                     ws_h, ws_as, ws_ad);
  hipLaunchKernelGGL(k2_gat, dim3(512), dim3(512), 0, stream,
                     ei, ws_h, ws_as, ws_ad, W_out, b_out, out);
}

// Round 5
// 96.575 us; speedup vs baseline: 1.2322x; 1.2322x over previous
//
#include <hip/hip_runtime.h>
#include <math.h>

// Problem constants
#define F_ 126
#define NPG 128              // nodes per graph
#define EPG 2048             // edges per graph
#define ET 524288            // total edges
#define NEG_SLOPE 0.2f

typedef short bf16x8 __attribute__((ext_vector_type(8)));
typedef float f32x4 __attribute__((ext_vector_type(4)));

__device__ __forceinline__ float bf2f(unsigned short u) {
  return __uint_as_float(((unsigned)u) << 16);
}
__device__ __forceinline__ unsigned short f2bf(float f) {
  unsigned x = __float_as_uint(f);
  unsigned r = x + 0x7fffu + ((x >> 16) & 1u);   // RNE
  return (unsigned short)(r >> 16);
}
// bank-spread swizzle on flat f32 indices (bijective within 512)
__device__ __forceinline__ int Fsw(int f) { return f ^ ((f & 0xE0) >> 3); }
#define SW(r) (((r) & 7) << 4)

// ---------------- K0: WcT[type][c][k] = (W_type @ W_gat)[k][c]  (bf16) -------------------
__global__ void k0_wct(const float* __restrict__ Wf, const float* __restrict__ Wu,
                       const float* __restrict__ Wi, const float* __restrict__ Wg,
                       unsigned short* __restrict__ wct) {
  int type = blockIdx.x >> 8;       // 0..2
  int c = blockIdx.x & 255;
  const float* Wx = (type == 0) ? Wf : ((type == 1) ? Wu : Wi);
  __shared__ float gcol[256];
  gcol[threadIdx.x] = Wg[threadIdx.x * 256 + c];
  __syncthreads();
  int k = threadIdx.x;
  const float4* wrow = reinterpret_cast<const float4*>(Wx + k * 256);
  float acc = 0.f;
#pragma unroll 8
  for (int j = 0; j < 64; ++j) {
    float4 v = wrow[j];
    acc += v.x * gcol[4 * j] + v.y * gcol[4 * j + 1] + v.z * gcol[4 * j + 2] + v.w * gcol[4 * j + 3];
  }
  wct[((size_t)type * 256 + c) * 256 + k] = f2bf(acc);
}

// ---------------- K2F: fully fused per-graph kernel --------------------------------------
// One block per graph. LDS regions (union across phases):
//   [0,64K):    Aemb bf16 [128 rows][256 k] (phase1)  ->  hT bf16 [256 dim][128 src] (phase2+)
//   [64K,128K): B-chunk bf16 [256 c][128 k] (phase1)  ->  A-alpha f32 [128 d][128 s] (phase3,
//               with bf16 copy overlaid in first 32K after cvt)
//   + small: as4/ad4/den (512 f32 each, Fsw), asl/adl/wout/lpart (256 f32 each)
#define OFF_HT   0
#define OFF_B    65536
#define OFF_AS   131072
#define OFF_AD   133120
#define OFF_DEN  135168
#define OFF_ASL  137216
#define OFF_ADL  138240
#define OFF_WOUT 139264
#define OFF_LP   140288
#define LDS_SZ   141312

__global__ __launch_bounds__(512, 2) void k2f(
    const int* __restrict__ fid, const int* __restrict__ userid, const int* __restrict__ itemid,
    const int* __restrict__ ei,
    const float* __restrict__ ftab, const float* __restrict__ utab, const float* __restrict__ itab,
    const unsigned short* __restrict__ wct,
    const float* __restrict__ a_src, const float* __restrict__ a_dst,
    const float* __restrict__ W_out, const float* __restrict__ b_out,
    float* __restrict__ out) {
  __shared__ __align__(16) char smem[LDS_SZ];
  const int g = blockIdx.x;
  const int tid = threadIdx.x;
  const int lane = tid & 63;
  const int wid = tid >> 6;
  const int rl = lane & 15;
  const int kg = lane >> 4;

  char* Ht = smem + OFF_HT;
  char* Bb = smem + OFF_B;
  float* as4 = (float*)(smem + OFF_AS);
  float* ad4 = (float*)(smem + OFF_AD);
  float* den = (float*)(smem + OFF_DEN);
  float* asl = (float*)(smem + OFF_ASL);
  float* adl = (float*)(smem + OFF_ADL);
  float* wo  = (float*)(smem + OFF_WOUT);
  float* lpf = (float*)(smem + OFF_LP);

  // edges -> registers (4 per thread), issued early
  int4 es = *(const int4*)(ei + (size_t)g * EPG + tid * 4);
  int4 ed = *(const int4*)(ei + (size_t)ET + (size_t)g * EPG + tid * 4);
  int se[4] = { es.x - g * NPG, es.y - g * NPG, es.z - g * NPG, es.w - g * NPG };
  int de[4] = { ed.x - g * NPG, ed.y - g * NPG, ed.z - g * NPG, ed.w - g * NPG };

  // small staging
  if (tid < 256) { asl[tid] = a_src[tid]; wo[tid] = W_out[tid]; }
  else           { adl[tid - 256] = a_dst[tid - 256]; }
  den[tid] = 0.f;
  const float bo = b_out[0];

  // ---- phase 1a: gather + cvt embedding rows -> Aemb (bf16, XOR-swizzled) ----
  {
    const int r = tid >> 2, q = tid & 3;
    const float* srcrow;
    if (r < F_)       srcrow = ftab + (size_t)fid[g * F_ + r] * 256;
    else if (r == F_) srcrow = utab + (size_t)userid[g] * 256;
    else              srcrow = itab + (size_t)itemid[g] * 256;
#pragma unroll
    for (int kc = 0; kc < 2; ++kc) {
      const float4* s4 = (const float4*)(srcrow + kc * 128 + q * 32);
#pragma unroll
      for (int i = 0; i < 8; ++i) {
        float4 v = s4[i];
        ushort4 b4 = { f2bf(v.x), f2bf(v.y), f2bf(v.z), f2bf(v.w) };
        int kk = kc * 128 + q * 32 + i * 4;
        *(ushort4*)(Ht + ((r * 512 + kk * 2) ^ SW(r))) = b4;
      }
    }
  }
  // ---- phase 1b: stage B chunk0 (wct type0, k in [0,128)) ----
  const int bc = tid >> 1, bh = tid & 1;
  {
    const uint4* bsrc = (const uint4*)(wct + (size_t)bc * 256 + bh * 64);
#pragma unroll
    for (int i = 0; i < 8; ++i) {
      int kk = bh * 64 + i * 8;
      *(uint4*)(Bb + ((bc * 256 + kk * 2) ^ SW(bc))) = bsrc[i];
    }
  }
  __syncthreads();

  // issue B chunk1 loads to regs (T14: hide under kc0 MFMA)
  uint4 b1[8];
  {
    const uint4* bsrc = (const uint4*)(wct + (size_t)bc * 256 + 128 + bh * 64);
#pragma unroll
    for (int i = 0; i < 8; ++i) b1[i] = bsrc[i];
  }

  const int mh = wid & 1, nq = wid >> 1;   // phase1 wave tile: 64 rows x 64 cols
  f32x4 acc[4][4] = {};

  // ---- phase 1c: MFMA kc=0 (A k-elems [0,128) paired with B chunk0) ----
#pragma unroll
  for (int ks = 0; ks < 4; ++ks) {
    bf16x8 af[4], bfv[4];
#pragma unroll
    for (int mf = 0; mf < 4; ++mf) {
      int row = mh * 64 + mf * 16 + rl;
      af[mf] = *(const bf16x8*)(Ht + ((row * 512 + (ks * 32 + kg * 8) * 2) ^ SW(row)));
    }
#pragma unroll
    for (int nf = 0; nf < 4; ++nf) {
      int cc = nq * 64 + nf * 16 + rl;
      bfv[nf] = *(const bf16x8*)(Bb + ((cc * 256 + (ks * 32 + kg * 8) * 2) ^ SW(cc)));
    }
#pragma unroll
    for (int mf = 0; mf < 4; ++mf)
#pragma unroll
      for (int nf = 0; nf < 4; ++nf)
        acc[mf][nf] = __builtin_amdgcn_mfma_f32_16x16x32_bf16(af[mf], bfv[nf], acc[mf][nf], 0, 0, 0);
  }
  __syncthreads();
  // write B chunk1
#pragma unroll
  for (int i = 0; i < 8; ++i) {
    int kk = bh * 64 + i * 8;
    *(uint4*)(Bb + ((bc * 256 + kk * 2) ^ SW(bc))) = b1[i];
  }
  __syncthreads();
  // ---- phase 1d: MFMA kc=1 (A k-elems [128,256): byte offset 256 + x*2) ----
#pragma unroll
  for (int ks = 0; ks < 4; ++ks) {
    bf16x8 af[4], bfv[4];
#pragma unroll
    for (int mf = 0; mf < 4; ++mf) {
      int row = mh * 64 + mf * 16 + rl;
      af[mf] = *(const bf16x8*)(Ht + ((row * 512 + (128 + ks * 32 + kg * 8) * 2) ^ SW(row)));
    }
#pragma unroll
    for (int nf = 0; nf < 4; ++nf) {
      int cc = nq * 64 + nf * 16 + rl;
      bfv[nf] = *(const bf16x8*)(Bb + ((cc * 256 + (ks * 32 + kg * 8) * 2) ^ SW(cc)));
    }
#pragma unroll
    for (int mf = 0; mf < 4; ++mf)
#pragma unroll
      for (int nf = 0; nf < 4; ++nf)
        acc[mf][nf] = __builtin_amdgcn_mfma_f32_16x16x32_bf16(af[mf], bfv[nf], acc[mf][nf], 0, 0, 0);
  }

  // ---- phase 1e: GEMV for user/item rows (correct per-type Wc) ----
  const int r2 = F_ + (tid >> 8);       // 126 or 127
  const int c2 = tid & 255;
  float hv = 0.f, gps, gpd;
  {
    const uint4* wrow = (const uint4*)(wct + ((size_t)(1 + (tid >> 8)) * 256 + c2) * 256);
#pragma unroll 4
    for (int i = 0; i < 32; ++i) {
      uint4 wv = wrow[i];
      uint4 av = *(const uint4*)(Ht + ((r2 * 512 + i * 16) ^ SW(r2)));
      const unsigned short* wp = (const unsigned short*)&wv;
      const unsigned short* ap = (const unsigned short*)&av;
#pragma unroll
      for (int j = 0; j < 8; ++j) hv += bf2f(ap[j]) * bf2f(wp[j]);
    }
    gps = hv * asl[c2];
    gpd = hv * adl[c2];
#pragma unroll
    for (int d = 32; d >= 1; d >>= 1) { gps += __shfl_xor(gps, d); gpd += __shfl_xor(gpd, d); }
  }

  // ---- phase 1f: as/ad from f32 acc (feature-path rows; skip 126/127) ----
  {
    float asv[4], adv[4];
#pragma unroll
    for (int nf = 0; nf < 4; ++nf) {
      asv[nf] = asl[nq * 64 + nf * 16 + rl];
      adv[nf] = adl[nq * 64 + nf * 16 + rl];
    }
#pragma unroll
    for (int mf = 0; mf < 4; ++mf) {
#pragma unroll
      for (int i = 0; i < 4; ++i) {
        float ps = 0.f, pd = 0.f;
#pragma unroll
        for (int nf = 0; nf < 4; ++nf) { float v = acc[mf][nf][i]; ps += v * asv[nf]; pd += v * adv[nf]; }
#pragma unroll
        for (int d = 1; d < 16; d <<= 1) { ps += __shfl_xor(ps, d); pd += __shfl_xor(pd, d); }
        int row = mh * 64 + mf * 16 + kg * 4 + i;
        if (rl == 0 && row < F_) { as4[Fsw(row * 4 + nq)] = ps; ad4[Fsw(row * 4 + nq)] = pd; }
      }
    }
  }
  if (lane == 0) { int h2 = wid & 3; as4[Fsw(r2 * 4 + h2)] = gps; ad4[Fsw(r2 * 4 + h2)] = gpd; }
  __syncthreads();   // all Aemb reads + as/ad writes done

  // ---- phase 2: build hT[dim][src] over the Aemb region ----
  {
#pragma unroll
    for (int mf = 0; mf < 4; ++mf) {
      int srcb = mh * 64 + mf * 16 + kg * 4;
#pragma unroll
      for (int nf = 0; nf < 4; ++nf) {
        int dim = nq * 64 + nf * 16 + rl;
        unsigned lo = (unsigned)f2bf(acc[mf][nf][0]) | ((unsigned)f2bf(acc[mf][nf][1]) << 16);
        unsigned hi = (unsigned)f2bf(acc[mf][nf][2]) | ((unsigned)f2bf(acc[mf][nf][3]) << 16);
        int bofs = (dim * 256 + srcb * 2) ^ SW(dim);
        if (srcb < 124) { uint2 u = { lo, hi }; *(uint2*)(Ht + bofs) = u; }
        else            { *(unsigned*)(Ht + bofs) = lo; }   // rows 124,125; 126/127 from GEMV
      }
    }
    *(unsigned short*)(Ht + ((c2 * 256 + r2 * 2) ^ SW(c2))) = f2bf(hv);
  }

  // ---- phase 3: 4 head passes: build A=exp(lrelu) -> cvt bf16 -> MFMA -> fused readout ----
  float lp[2][4] = {};
  const int m2 = (wid & 3) * 32, n2 = (wid >> 2) * 32;

  for (int hd = 0; hd < 4; ++hd) {
    __syncthreads();                       // prev pass GEMM done with Bb; phase2 writes done
    {
      uint4 z = { 0, 0, 0, 0 };
#pragma unroll
      for (int i = 0; i < 8; ++i) *(uint4*)(Bb + tid * 128 + i * 16) = z;
    }
    __syncthreads();
    // scatter exp weights (duplicates merge via +=)
#pragma unroll
    for (int j = 0; j < 4; ++j) {
      int s = se[j], d = de[j];
      float e = as4[Fsw(s * 4 + hd)] + ad4[Fsw(d * 4 + hd)];
      e = (e < 0.f) ? NEG_SLOPE * e : e;
      float w = __expf(e);
      atomicAdd((float*)(Bb + ((d * 512 + s * 4) ^ SW(d))), w);
      atomicAdd(&den[Fsw(d * 4 + hd)], w);
    }
    __syncthreads();
    // in-place f32 -> bf16 cvt (read-all, barrier, write-all)
    {
      const int dd = tid >> 2, qq = tid & 3;
      uint4 rv[8];
#pragma unroll
      for (int i = 0; i < 8; ++i)
        rv[i] = *(const uint4*)(Bb + ((dd * 512 + qq * 128 + i * 16) ^ SW(dd)));
      __syncthreads();
#pragma unroll
      for (int i = 0; i < 4; ++i) {
        const float* f0 = (const float*)&rv[2 * i];
        const float* f1 = (const float*)&rv[2 * i + 1];
        uint4 o;
        o.x = (unsigned)f2bf(f0[0]) | ((unsigned)f2bf(f0[1]) << 16);
        o.y = (unsigned)f2bf(f0[2]) | ((unsigned)f2bf(f0[3]) << 16);
        o.z = (unsigned)f2bf(f1[0]) | ((unsigned)f2bf(f1[1]) << 16);
        o.w = (unsigned)f2bf(f1[2]) | ((unsigned)f2bf(f1[3]) << 16);
        *(uint4*)(Bb + ((dd * 256 + (qq * 32 + i * 8) * 2) ^ SW(dd))) = o;
      }
    }
    __syncthreads();
    // GEMM: out_head[128 x 64] = A[128 x 128] @ h_head[128 x 64]
    f32x4 acc2[2][2] = {};
#pragma unroll
    for (int ks = 0; ks < 4; ++ks) {
      bf16x8 a2[2], b2[2];
#pragma unroll
      for (int mf = 0; mf < 2; ++mf) {
        int row = m2 + mf * 16 + rl;
        a2[mf] = *(const bf16x8*)(Bb + ((row * 256 + (ks * 32 + kg * 8) * 2) ^ SW(row)));
      }
#pragma unroll
      for (int nf = 0; nf < 2; ++nf) {
        int dim = hd * 64 + n2 + nf * 16 + rl;
        b2[nf] = *(const bf16x8*)(Ht + ((dim * 256 + (ks * 32 + kg * 8) * 2) ^ SW(dim)));
      }
#pragma unroll
      for (int mf = 0; mf < 2; ++mf)
#pragma unroll
        for (int nf = 0; nf < 2; ++nf)
          acc2[mf][nf] = __builtin_amdgcn_mfma_f32_16x16x32_bf16(a2[mf], b2[nf], acc2[mf][nf], 0, 0, 0);
    }
    // fused normalize + ELU + readout accumulate
#pragma unroll
    for (int mf = 0; mf < 2; ++mf) {
#pragma unroll
      for (int i = 0; i < 4; ++i) {
        int row = m2 + mf * 16 + kg * 4 + i;
        float rd = __builtin_amdgcn_rcpf(den[Fsw(row * 4 + hd)] + 1e-16f);
#pragma unroll
        for (int nf = 0; nf < 2; ++nf) {
          float v = acc2[mf][nf][i] * rd;
          v = (v > 0.f) ? v : (__expf(v) - 1.f);
          lp[mf][i] += v * wo[hd * 64 + n2 + nf * 16 + rl];
        }
      }
    }
  }

  // ---- phase 4: reduce readout partials, write logits ----
#pragma unroll
  for (int mf = 0; mf < 2; ++mf) {
#pragma unroll
    for (int i = 0; i < 4; ++i) {
      float v = lp[mf][i];
#pragma unroll
      for (int d = 1; d < 16; d <<= 1) v += __shfl_xor(v, d);
      if (rl == 0) {
        int row = m2 + mf * 16 + kg * 4 + i;
        lpf[row * 2 + (wid >> 2)] = v;
      }
    }
  }
  __syncthreads();
  if (tid < F_) out[(size_t)g * F_ + tid] = lpf[tid * 2] + lpf[tid * 2 + 1] + bo;
}

extern "C" void kernel_launch(void* const* d_in, const int* in_sizes, int n_in,
                              void* d_out, int out_size, void* d_ws, size_t ws_size,
                              hipStream_t stream) {
  const int* fid      = (const int*)d_in[0];
  const int* userid   = (const int*)d_in[1];
  const int* itemid   = (const int*)d_in[2];
  const int* ei       = (const int*)d_in[3];
  const float* ftab   = (const float*)d_in[4];
  const float* utab   = (const float*)d_in[5];
  const float* itab   = (const float*)d_in[6];
  const float* Wf     = (const float*)d_in[7];
  const float* Wu     = (const float*)d_in[8];
  const float* Wi     = (const float*)d_in[9];
  const float* Wg     = (const float*)d_in[10];
  const float* a_src  = (const float*)d_in[11];
  const float* a_dst  = (const float*)d_in[12];
  const float* W_out  = (const float*)d_in[13];
  const float* b_out  = (const float*)d_in[14];
  float* out = (float*)d_out;

  // ws: WcT bf16 3*[256][256] (384 KB)
  unsigned short* ws_wct = (unsigned short*)d_ws;

  hipLaunchKernelGGL(k0_wct, dim3(768), dim3(256), 0, stream, Wf, Wu, Wi, Wg, ws_wct);
  hipLaunchKernelGGL(k2f, dim3(256), dim3(512), 0, stream,
                     fid, userid, itemid, ei, ftab, utab, itab, ws_wct,
                     a_src, a_dst, W_out, b_out, out);
}

// Round 7
// 82.606 us; speedup vs baseline: 1.4406x; 1.1691x over previous
//
#include <hip/hip_runtime.h>
#include <math.h>

// Problem constants
#define F_ 126
#define NPG 128              // nodes per graph
#define EPG 2048             // edges per graph
#define ET 524288            // total edges
#define NEG_SLOPE 0.2f

typedef short bf16x8 __attribute__((ext_vector_type(8)));
typedef float f32x4 __attribute__((ext_vector_type(4)));

__device__ __forceinline__ float bf2f(unsigned short u) {
  return __uint_as_float(((unsigned)u) << 16);
}
__device__ __forceinline__ unsigned short f2bf(float f) {
  unsigned x = __float_as_uint(f);
  unsigned r = x + 0x7fffu + ((x >> 16) & 1u);   // RNE
  return (unsigned short)(r >> 16);
}
// bank-spread swizzle on flat f32 indices (bijective within 512)
__device__ __forceinline__ int Fsw(int f) { return f ^ ((f & 0xE0) >> 3); }
#define SW(r) (((r) & 7) << 4)

// ---------------- K0: WcT[type][c][k] = (W_type @ W_gat)[k][c]  (bf16) -------------------
// 96 blocks = 3 types x 32 col-groups of 8. Wg chunk transposed in LDS; per-thread 8 dots.
__global__ __launch_bounds__(256) void k0_wct(const float* __restrict__ Wf,
                                              const float* __restrict__ Wu,
                                              const float* __restrict__ Wi,
                                              const float* __restrict__ Wg,
                                              unsigned short* __restrict__ wct) {
  const int blk = blockIdx.x;
  const int type = blk >> 5;
  const int cg = (blk & 31) * 8;
  const float* Wx = (type == 0) ? Wf : ((type == 1) ? Wu : Wi);
  __shared__ float gT[8][256];      // gT[cc][j] = Wg[j][cg+cc]
#pragma unroll
  for (int cc = 0; cc < 8; ++cc) gT[cc][threadIdx.x] = Wg[threadIdx.x * 256 + cg + cc];
  __syncthreads();
  const int k = threadIdx.x;
  const float4* wrow = reinterpret_cast<const float4*>(Wx + k * 256);
  float acc[8] = {};
  for (int j4 = 0; j4 < 64; ++j4) {
    float4 v = wrow[j4];
#pragma unroll
    for (int cc = 0; cc < 8; ++cc) {
      float4 gv = *reinterpret_cast<const float4*>(&gT[cc][j4 * 4]);
      acc[cc] += v.x * gv.x + v.y * gv.y + v.z * gv.z + v.w * gv.w;
    }
  }
#pragma unroll
  for (int cc = 0; cc < 8; ++cc)
    wct[((size_t)type * 256 + cg + cc) * 256 + k] = f2bf(acc[cc]);
}

// ---------------- K2F: fully fused per-graph kernel, 1024 threads ------------------------
// One block per graph (256 blocks, 1 block/CU, 16 waves).
#define OFF_HT   0
#define OFF_B    65536
#define OFF_AS   131072
#define OFF_AD   133120
#define OFF_DEN  135168
#define OFF_ASL  137216
#define OFF_ADL  138240
#define OFF_WOUT 139264
#define OFF_LP   140288
#define LDS_SZ   141312

__global__ __launch_bounds__(1024, 1) void k2f(
    const int* __restrict__ fid, const int* __restrict__ userid, const int* __restrict__ itemid,
    const int* __restrict__ ei,
    const float* __restrict__ ftab, const float* __restrict__ utab, const float* __restrict__ itab,
    const unsigned short* __restrict__ wct,
    const float* __restrict__ a_src, const float* __restrict__ a_dst,
    const float* __restrict__ W_out, const float* __restrict__ b_out,
    float* __restrict__ out) {
  __shared__ __align__(16) char smem[LDS_SZ];
  const int g = blockIdx.x;
  const int tid = threadIdx.x;
  const int lane = tid & 63;
  const int wid = tid >> 6;          // 0..15
  const int rl = lane & 15;
  const int kg = lane >> 4;

  char* Ht = smem + OFF_HT;          // Aemb [128][256] bf16 -> hT [256][128] bf16
  char* Bb = smem + OFF_B;           // B [256][128k] bf16 -> A f32 [128][128] / A bf16
  float* as4 = (float*)(smem + OFF_AS);
  float* ad4 = (float*)(smem + OFF_AD);
  float* den = (float*)(smem + OFF_DEN);
  float* asl = (float*)(smem + OFF_ASL);
  float* adl = (float*)(smem + OFF_ADL);
  float* wo  = (float*)(smem + OFF_WOUT);
  float* lpf = (float*)(smem + OFF_LP);

  // edges -> registers (2 per thread)
  int2 es = *(const int2*)(ei + (size_t)g * EPG + tid * 2);
  int2 ed = *(const int2*)(ei + (size_t)ET + (size_t)g * EPG + tid * 2);
  int se[2] = { es.x - g * NPG, es.y - g * NPG };
  int de[2] = { ed.x - g * NPG, ed.y - g * NPG };

  // small staging
  if (tid < 256)      { asl[tid] = a_src[tid]; wo[tid] = W_out[tid]; }
  else if (tid < 512) { adl[tid - 256] = a_dst[tid - 256]; }
  if (tid < 512) den[tid] = 0.f;     // ALL 512 entries (Fsw spans [0,512))
  const float bo = b_out[0];

  // ---- phase 1a: gather + cvt embedding rows -> Aemb (8 threads/row) ----
  {
    const int r = tid >> 3, q = tid & 7;
    const float* srcrow;
    if (r < F_)       srcrow = ftab + (size_t)fid[g * F_ + r] * 256;
    else if (r == F_) srcrow = utab + (size_t)userid[g] * 256;
    else              srcrow = itab + (size_t)itemid[g] * 256;
#pragma unroll
    for (int i = 0; i < 4; ++i) {
      // floats [i*64 + q*8, +8)
      float4 v0 = *(const float4*)(srcrow + i * 64 + q * 8);
      float4 v1 = *(const float4*)(srcrow + i * 64 + q * 8 + 4);
      uint4 o;
      o.x = (unsigned)f2bf(v0.x) | ((unsigned)f2bf(v0.y) << 16);
      o.y = (unsigned)f2bf(v0.z) | ((unsigned)f2bf(v0.w) << 16);
      o.z = (unsigned)f2bf(v1.x) | ((unsigned)f2bf(v1.y) << 16);
      o.w = (unsigned)f2bf(v1.z) | ((unsigned)f2bf(v1.w) << 16);
      *(uint4*)(Ht + ((r * 512 + i * 128 + q * 16) ^ SW(r))) = o;
    }
  }
  // ---- phase 1b: stage B chunk0 (k in [0,128)), 4 threads/col ----
  const int bc = tid >> 2, bh = tid & 3;
  {
#pragma unroll
    for (int i = 0; i < 4; ++i) {
      uint4 v = *(const uint4*)(wct + (size_t)bc * 256 + bh * 32 + i * 8);
      *(uint4*)(Bb + ((bc * 256 + bh * 64 + i * 16) ^ SW(bc))) = v;
    }
  }
  __syncthreads();

  // prefetch B chunk1 to regs (hide under kc0 MFMA)
  uint4 b1[4];
#pragma unroll
  for (int i = 0; i < 4; ++i)
    b1[i] = *(const uint4*)(wct + (size_t)bc * 256 + 128 + bh * 32 + i * 8);

  // phase-1 wave tile: rows mh*32 (2 mf frags), cols nq*64 (4 nf frags) == head nq
  const int mh = wid & 3, nq = wid >> 2;
  f32x4 acc[2][4] = {};

  // ---- phase 1c/1d: MFMA over 2 K-chunks ----
#pragma unroll
  for (int ks = 0; ks < 4; ++ks) {
    bf16x8 af[2], bfv[4];
#pragma unroll
    for (int mf = 0; mf < 2; ++mf) {
      int row = mh * 32 + mf * 16 + rl;
      af[mf] = *(const bf16x8*)(Ht + ((row * 512 + (ks * 32 + kg * 8) * 2) ^ SW(row)));
    }
#pragma unroll
    for (int nf = 0; nf < 4; ++nf) {
      int cc = nq * 64 + nf * 16 + rl;
      bfv[nf] = *(const bf16x8*)(Bb + ((cc * 256 + (ks * 32 + kg * 8) * 2) ^ SW(cc)));
    }
#pragma unroll
    for (int mf = 0; mf < 2; ++mf)
#pragma unroll
      for (int nf = 0; nf < 4; ++nf)
        acc[mf][nf] = __builtin_amdgcn_mfma_f32_16x16x32_bf16(af[mf], bfv[nf], acc[mf][nf], 0, 0, 0);
  }
  __syncthreads();
#pragma unroll
  for (int i = 0; i < 4; ++i)
    *(uint4*)(Bb + ((bc * 256 + bh * 64 + i * 16) ^ SW(bc))) = b1[i];
  __syncthreads();
#pragma unroll
  for (int ks = 0; ks < 4; ++ks) {
    bf16x8 af[2], bfv[4];
#pragma unroll
    for (int mf = 0; mf < 2; ++mf) {
      int row = mh * 32 + mf * 16 + rl;
      af[mf] = *(const bf16x8*)(Ht + ((row * 512 + 256 + (ks * 32 + kg * 8) * 2) ^ SW(row)));
    }
#pragma unroll
    for (int nf = 0; nf < 4; ++nf) {
      int cc = nq * 64 + nf * 16 + rl;
      bfv[nf] = *(const bf16x8*)(Bb + ((cc * 256 + (ks * 32 + kg * 8) * 2) ^ SW(cc)));
    }
#pragma unroll
    for (int mf = 0; mf < 2; ++mf)
#pragma unroll
      for (int nf = 0; nf < 4; ++nf)
        acc[mf][nf] = __builtin_amdgcn_mfma_f32_16x16x32_bf16(af[mf], bfv[nf], acc[mf][nf], 0, 0, 0);
  }

  // ---- phase 1e: GEMV for user/item rows (threads 0..511) ----
  const int r2 = F_ + ((tid >> 8) & 1);
  const int c2 = tid & 255;
  float hv = 0.f;
  if (tid < 512) {
    float gps, gpd;
    const uint4* wrow = (const uint4*)(wct + ((size_t)(1 + (tid >> 8)) * 256 + c2) * 256);
#pragma unroll 4
    for (int i = 0; i < 32; ++i) {
      uint4 wv = wrow[i];
      uint4 av = *(const uint4*)(Ht + ((r2 * 512 + i * 16) ^ SW(r2)));
      const unsigned short* wp = (const unsigned short*)&wv;
      const unsigned short* ap = (const unsigned short*)&av;
#pragma unroll
      for (int j = 0; j < 8; ++j) hv += bf2f(ap[j]) * bf2f(wp[j]);
    }
    gps = hv * asl[c2];
    gpd = hv * adl[c2];
#pragma unroll
    for (int d = 32; d >= 1; d >>= 1) { gps += __shfl_xor(gps, d); gpd += __shfl_xor(gpd, d); }
    if (lane == 0) { int h2 = wid & 3; as4[Fsw(r2 * 4 + h2)] = gps; ad4[Fsw(r2 * 4 + h2)] = gpd; }
  }

  // ---- phase 1f: as/ad from f32 acc (head = nq) ----
  {
    float asv[4], adv[4];
#pragma unroll
    for (int nf = 0; nf < 4; ++nf) {
      asv[nf] = asl[nq * 64 + nf * 16 + rl];
      adv[nf] = adl[nq * 64 + nf * 16 + rl];
    }
#pragma unroll
    for (int mf = 0; mf < 2; ++mf) {
#pragma unroll
      for (int i = 0; i < 4; ++i) {
        float ps = 0.f, pd = 0.f;
#pragma unroll
        for (int nf = 0; nf < 4; ++nf) { float v = acc[mf][nf][i]; ps += v * asv[nf]; pd += v * adv[nf]; }
#pragma unroll
        for (int d = 1; d < 16; d <<= 1) { ps += __shfl_xor(ps, d); pd += __shfl_xor(pd, d); }
        int row = mh * 32 + mf * 16 + kg * 4 + i;
        if (rl == 0 && row < F_) { as4[Fsw(row * 4 + nq)] = ps; ad4[Fsw(row * 4 + nq)] = pd; }
      }
    }
  }
  __syncthreads();   // all Aemb reads + as/ad writes done

  // ---- phase 2: build hT[dim][src] over the Aemb region ----
  {
#pragma unroll
    for (int mf = 0; mf < 2; ++mf) {
      int srcb = mh * 32 + mf * 16 + kg * 4;
#pragma unroll
      for (int nf = 0; nf < 4; ++nf) {
        int dim = nq * 64 + nf * 16 + rl;
        unsigned lo = (unsigned)f2bf(acc[mf][nf][0]) | ((unsigned)f2bf(acc[mf][nf][1]) << 16);
        unsigned hi = (unsigned)f2bf(acc[mf][nf][2]) | ((unsigned)f2bf(acc[mf][nf][3]) << 16);
        int bofs = (dim * 256 + srcb * 2) ^ SW(dim);
        if (srcb < 124) { uint2 u = { lo, hi }; *(uint2*)(Ht + bofs) = u; }
        else            { *(unsigned*)(Ht + bofs) = lo; }   // src 124,125; 126/127 from GEMV
      }
    }
    if (tid < 512)
      *(unsigned short*)(Ht + ((c2 * 256 + r2 * 2) ^ SW(c2))) = f2bf(hv);
  }

  // ---- phase 3: 4 head passes ----
  float lp[4] = {};
  const int m2 = (wid & 7) * 16, n2 = (wid >> 3) * 32;
  const int dd = tid >> 3, qq = tid & 7;

  for (int hd = 0; hd < 4; ++hd) {
    __syncthreads();                       // prev GEMM done with Bb; phase2 writes done
    // zero A_f32 (conflict-free linear)
    {
      uint4 z = { 0, 0, 0, 0 };
#pragma unroll
      for (int i = 0; i < 4; ++i) *(uint4*)(Bb + tid * 16 + i * 16384) = z;
    }
    __syncthreads();
    // scatter exp weights (duplicates merge via +=)
#pragma unroll
    for (int j = 0; j < 2; ++j) {
      int s = se[j], d = de[j];
      float e = as4[Fsw(s * 4 + hd)] + ad4[Fsw(d * 4 + hd)];
      e = (e < 0.f) ? NEG_SLOPE * e : e;
      float w = __expf(e);
      atomicAdd((float*)(Bb + ((d * 512 + s * 4) ^ SW(d))), w);
      atomicAdd(&den[Fsw(d * 4 + hd)], w);
    }
    __syncthreads();
    // in-place f32 -> bf16 cvt (8 threads/row, lane-consecutive 16B)
    {
      uint4 rv[2][2];
#pragma unroll
      for (int j = 0; j < 2; ++j) {
        rv[j][0] = *(const uint4*)(Bb + ((dd * 512 + qq * 32 + j * 256) ^ SW(dd)));
        rv[j][1] = *(const uint4*)(Bb + ((dd * 512 + qq * 32 + j * 256 + 16) ^ SW(dd)));
      }
      __syncthreads();
#pragma unroll
      for (int j = 0; j < 2; ++j) {
        const float* f0 = (const float*)&rv[j][0];
        const float* f1 = (const float*)&rv[j][1];
        uint4 o;
        o.x = (unsigned)f2bf(f0[0]) | ((unsigned)f2bf(f0[1]) << 16);
        o.y = (unsigned)f2bf(f0[2]) | ((unsigned)f2bf(f0[3]) << 16);
        o.z = (unsigned)f2bf(f1[0]) | ((unsigned)f2bf(f1[1]) << 16);
        o.w = (unsigned)f2bf(f1[2]) | ((unsigned)f2bf(f1[3]) << 16);
        *(uint4*)(Bb + ((dd * 256 + (qq + j * 8) * 16) ^ SW(dd))) = o;
      }
    }
    __syncthreads();
    // GEMM: out_head[128 x 64] = A[128 x 128] @ hT_head^T ; wave tile 16x32
    f32x4 acc2[2] = {};
#pragma unroll
    for (int ks = 0; ks < 4; ++ks) {
      int row = m2 + rl;
      bf16x8 a2 = *(const bf16x8*)(Bb + ((row * 256 + (ks * 32 + kg * 8) * 2) ^ SW(row)));
      bf16x8 b2[2];
#pragma unroll
      for (int nf = 0; nf < 2; ++nf) {
        int dim = hd * 64 + n2 + nf * 16 + rl;
        b2[nf] = *(const bf16x8*)(Ht + ((dim * 256 + (ks * 32 + kg * 8) * 2) ^ SW(dim)));
      }
#pragma unroll
      for (int nf = 0; nf < 2; ++nf)
        acc2[nf] = __builtin_amdgcn_mfma_f32_16x16x32_bf16(a2, b2[nf], acc2[nf], 0, 0, 0);
    }
    // fused normalize + ELU + readout accumulate
#pragma unroll
    for (int i = 0; i < 4; ++i) {
      int row = m2 + kg * 4 + i;
      float rd = __builtin_amdgcn_rcpf(den[Fsw(row * 4 + hd)] + 1e-16f);
#pragma unroll
      for (int nf = 0; nf < 2; ++nf) {
        float v = acc2[nf][i] * rd;
        v = (v > 0.f) ? v : (__expf(v) - 1.f);
        lp[i] += v * wo[hd * 64 + n2 + nf * 16 + rl];
      }
    }
  }

  // ---- phase 4: reduce readout partials, write logits ----
#pragma unroll
  for (int i = 0; i < 4; ++i) {
    float v = lp[i];
#pragma unroll
    for (int d = 1; d < 16; d <<= 1) v += __shfl_xor(v, d);
    if (rl == 0) lpf[(m2 + kg * 4 + i) * 2 + (wid >> 3)] = v;
  }
  __syncthreads();
  if (tid < F_) out[(size_t)g * F_ + tid] = lpf[tid * 2] + lpf[tid * 2 + 1] + bo;
}

extern "C" void kernel_launch(void* const* d_in, const int* in_sizes, int n_in,
                              void* d_out, int out_size, void* d_ws, size_t ws_size,
                              hipStream_t stream) {
  const int* fid      = (const int*)d_in[0];
  const int* userid   = (const int*)d_in[1];
  const int* itemid   = (const int*)d_in[2];
  const int* ei       = (const int*)d_in[3];
  const float* ftab   = (const float*)d_in[4];
  const float* utab   = (const float*)d_in[5];
  const float* itab   = (const float*)d_in[6];
  const float* Wf     = (const float*)d_in[7];
  const float* Wu     = (const float*)d_in[8];
  const float* Wi     = (const float*)d_in[9];
  const float* Wg     = (const float*)d_in[10];
  const float* a_src  = (const float*)d_in[11];
  const float* a_dst  = (const float*)d_in[12];
  const float* W_out  = (const float*)d_in[13];
  const float* b_out  = (const float*)d_in[14];
  float* out = (float*)d_out;

  // ws: WcT bf16 3*[256][256] (384 KB)
  unsigned short* ws_wct = (unsigned short*)d_ws;

  hipLaunchKernelGGL(k0_wct, dim3(96), dim3(256), 0, stream, Wf, Wu, Wi, Wg, ws_wct);
  hipLaunchKernelGGL(k2f, dim3(256), dim3(1024), 0, stream,
                     fid, userid, itemid, ei, ftab, utab, itab, ws_wct,
                     a_src, a_dst, W_out, b_out, out);
}

// Round 8
// 76.155 us; speedup vs baseline: 1.5627x; 1.0847x over previous
//
#include <hip/hip_runtime.h>
#include <math.h>

// Problem constants
#define F_ 126
#define NPG 128              // nodes per graph
#define EPG 2048             // edges per graph
#define ET 524288            // total edges
#define NEG_SLOPE 0.2f

typedef short bf16x8 __attribute__((ext_vector_type(8)));
typedef float f32x4 __attribute__((ext_vector_type(4)));

__device__ __forceinline__ float bf2f(unsigned short u) {
  return __uint_as_float(((unsigned)u) << 16);
}
__device__ __forceinline__ unsigned short f2bf(float f) {
  unsigned x = __float_as_uint(f);
  unsigned r = x + 0x7fffu + ((x >> 16) & 1u);   // RNE
  return (unsigned short)(r >> 16);
}
#define SW(r) (((r) & 7) << 4)

// ---------------- K0: WcT[type][c][k] = (W_type @ W_gat)[k][c]  (bf16) -------------------
__global__ __launch_bounds__(256) void k0_wct(const float* __restrict__ Wf,
                                              const float* __restrict__ Wu,
                                              const float* __restrict__ Wi,
                                              const float* __restrict__ Wg,
                                              unsigned short* __restrict__ wct) {
  const int blk = blockIdx.x;
  const int type = blk >> 5;
  const int cg = (blk & 31) * 8;
  const float* Wx = (type == 0) ? Wf : ((type == 1) ? Wu : Wi);
  __shared__ float gT[8][256];
#pragma unroll
  for (int cc = 0; cc < 8; ++cc) gT[cc][threadIdx.x] = Wg[threadIdx.x * 256 + cg + cc];
  __syncthreads();
  const int k = threadIdx.x;
  const float4* wrow = reinterpret_cast<const float4*>(Wx + k * 256);
  float acc[8] = {};
  for (int j4 = 0; j4 < 64; ++j4) {
    float4 v = wrow[j4];
#pragma unroll
    for (int cc = 0; cc < 8; ++cc) {
      float4 gv = *reinterpret_cast<const float4*>(&gT[cc][j4 * 4]);
      acc[cc] += v.x * gv.x + v.y * gv.y + v.z * gv.z + v.w * gv.w;
    }
  }
#pragma unroll
  for (int cc = 0; cc < 8; ++cc)
    wct[((size_t)type * 256 + cg + cc) * 256 + k] = f2bf(acc[cc]);
}

// ---------------- K2F: fused per-graph kernel, minimal-barrier structure ------------------
// LDS: hT bf16 [256 dim][128 src] @0 (64KB); M @65536: int [128][128] (64KB) during scatter,
//      then bf16 [128][128] (32KB, compacted in place); asT/adT f32 [4][128]; asl/adl/wout/lpf.
#define OFF_HT   0
#define OFF_M    65536
#define OFF_AST  131072
#define OFF_ADT  133120
#define OFF_ASL  135168
#define OFF_ADL  136192
#define OFF_WOUT 137216
#define OFF_LP   138240
#define LDS_SZ   139264

__global__ __launch_bounds__(1024, 1) void k2f(
    const int* __restrict__ fid, const int* __restrict__ userid, const int* __restrict__ itemid,
    const int* __restrict__ ei,
    const float* __restrict__ ftab, const float* __restrict__ utab, const float* __restrict__ itab,
    const unsigned short* __restrict__ wct,
    const float* __restrict__ a_src, const float* __restrict__ a_dst,
    const float* __restrict__ W_out, const float* __restrict__ b_out,
    float* __restrict__ out) {
  __shared__ __align__(16) char smem[LDS_SZ];
  const int g = blockIdx.x;
  const int tid = threadIdx.x;
  const int lane = tid & 63;
  const int wid = tid >> 6;          // 0..15
  const int rl = lane & 15;
  const int kg = lane >> 4;

  char* Ht = smem + OFF_HT;
  char* Mb = smem + OFF_M;
  float* asT = (float*)(smem + OFF_AST);   // asT[hd*128 + node]
  float* adT = (float*)(smem + OFF_ADT);
  float* asl = (float*)(smem + OFF_ASL);
  float* adl = (float*)(smem + OFF_ADL);
  float* wo  = (float*)(smem + OFF_WOUT);
  float* lpf = (float*)(smem + OFF_LP);

  // edges -> registers (2 per thread)
  int2 es = *(const int2*)(ei + (size_t)g * EPG + tid * 2);
  int2 ed = *(const int2*)(ei + (size_t)ET + (size_t)g * EPG + tid * 2);
  int se[2] = { es.x - g * NPG, es.y - g * NPG };
  int de[2] = { ed.x - g * NPG, ed.y - g * NPG };

  // staging + zero M (int)
  if (tid < 256)      { asl[tid] = a_src[tid]; wo[tid] = W_out[tid]; }
  else if (tid < 512) { adl[tid - 256] = a_dst[tid - 256]; }
  {
    uint4 z = { 0, 0, 0, 0 };
#pragma unroll
    for (int i = 0; i < 4; ++i) *(uint4*)(Mb + tid * 16 + i * 16384) = z;
  }
  const float bo = b_out[0];
  __syncthreads();                                 // b0: M zeroed, asl/adl staged

  // scatter multiplicity M (head-independent) -- atomics hide under GEMM1 below
#pragma unroll
  for (int j = 0; j < 2; ++j)
    atomicAdd((int*)(Mb + ((de[j] * 512 + se[j] * 4) ^ SW(de[j]))), 1);

  // ---- GEMM1, fully in-register operands: h = emb @ Wc(type0) ----
  const int mh = wid & 3, nq = wid >> 2;           // rows mh*32..+32, cols nq*64..+64 (head nq)
  f32x4 acc[2][4] = {};
  const float* rp[2];
#pragma unroll
  for (int mf = 0; mf < 2; ++mf) {
    int row = mh * 32 + mf * 16 + rl;
    if (row < F_)       rp[mf] = ftab + (size_t)fid[g * F_ + row] * 256;
    else if (row == F_) rp[mf] = utab + (size_t)userid[g] * 256;   // overwritten by GEMV
    else                rp[mf] = itab + (size_t)itemid[g] * 256;
  }
  const unsigned short* bp[4];
#pragma unroll
  for (int nf = 0; nf < 4; ++nf)
    bp[nf] = wct + (size_t)(nq * 64 + nf * 16 + rl) * 256;

#pragma unroll
  for (int ks = 0; ks < 8; ++ks) {
    bf16x8 af[2], bfv[4];
#pragma unroll
    for (int mf = 0; mf < 2; ++mf) {
      float4 v0 = *(const float4*)(rp[mf] + ks * 32 + kg * 8);
      float4 v1 = *(const float4*)(rp[mf] + ks * 32 + kg * 8 + 4);
      af[mf][0] = (short)f2bf(v0.x); af[mf][1] = (short)f2bf(v0.y);
      af[mf][2] = (short)f2bf(v0.z); af[mf][3] = (short)f2bf(v0.w);
      af[mf][4] = (short)f2bf(v1.x); af[mf][5] = (short)f2bf(v1.y);
      af[mf][6] = (short)f2bf(v1.z); af[mf][7] = (short)f2bf(v1.w);
    }
#pragma unroll
    for (int nf = 0; nf < 4; ++nf)
      bfv[nf] = *(const bf16x8*)(bp[nf] + ks * 32 + kg * 8);
#pragma unroll
    for (int mf = 0; mf < 2; ++mf)
#pragma unroll
      for (int nf = 0; nf < 4; ++nf)
        acc[mf][nf] = __builtin_amdgcn_mfma_f32_16x16x32_bf16(af[mf], bfv[nf], acc[mf][nf], 0, 0, 0);
  }

  // ---- as/ad from f32 acc (head = nq); write asT/adT ----
  {
    float asv[4], adv[4];
#pragma unroll
    for (int nf = 0; nf < 4; ++nf) {
      asv[nf] = asl[nq * 64 + nf * 16 + rl];
      adv[nf] = adl[nq * 64 + nf * 16 + rl];
    }
#pragma unroll
    for (int mf = 0; mf < 2; ++mf) {
#pragma unroll
      for (int i = 0; i < 4; ++i) {
        float ps = 0.f, pd = 0.f;
#pragma unroll
        for (int nf = 0; nf < 4; ++nf) { float v = acc[mf][nf][i]; ps += v * asv[nf]; pd += v * adv[nf]; }
#pragma unroll
        for (int d2 = 1; d2 < 16; d2 <<= 1) { ps += __shfl_xor(ps, d2); pd += __shfl_xor(pd, d2); }
        int row = mh * 32 + mf * 16 + kg * 4 + i;
        if (rl == 0 && row < F_) { asT[nq * 128 + row] = ps; adT[nq * 128 + row] = pd; }
      }
    }
  }

  // ---- transpose-write hT[dim][src] ----
  {
#pragma unroll
    for (int mf = 0; mf < 2; ++mf) {
      int srcb = mh * 32 + mf * 16 + kg * 4;
#pragma unroll
      for (int nf = 0; nf < 4; ++nf) {
        int dim = nq * 64 + nf * 16 + rl;
        unsigned lo = (unsigned)f2bf(acc[mf][nf][0]) | ((unsigned)f2bf(acc[mf][nf][1]) << 16);
        unsigned hi = (unsigned)f2bf(acc[mf][nf][2]) | ((unsigned)f2bf(acc[mf][nf][3]) << 16);
        int bofs = (dim * 256 + srcb * 2) ^ SW(dim);
        if (srcb < 124) { uint2 u = { lo, hi }; *(uint2*)(Ht + bofs) = u; }
        else            { *(unsigned*)(Ht + bofs) = lo; }   // src 124,125; 126/127 via GEMV
      }
    }
  }

  // ---- GEMV for user/item source rows (threads 0..511), reg-direct ----
  if (tid < 512) {
    const int r2 = F_ + (tid >> 8);
    const int c2 = tid & 255;
    const float* er = (tid < 256) ? (utab + (size_t)userid[g] * 256)
                                  : (itab + (size_t)itemid[g] * 256);
    const uint4* wr = (const uint4*)(wct + (size_t)(1 + (tid >> 8)) * 65536 + (size_t)c2 * 256);
    const float4* e4 = (const float4*)er;
    float hv = 0.f;
#pragma unroll 4
    for (int j = 0; j < 32; ++j) {
      uint4 w8 = wr[j];
      float4 e0 = e4[2 * j], e1 = e4[2 * j + 1];
      const unsigned short* wp = (const unsigned short*)&w8;
      hv += e0.x * bf2f(wp[0]) + e0.y * bf2f(wp[1]) + e0.z * bf2f(wp[2]) + e0.w * bf2f(wp[3]);
      hv += e1.x * bf2f(wp[4]) + e1.y * bf2f(wp[5]) + e1.z * bf2f(wp[6]) + e1.w * bf2f(wp[7]);
    }
    float gps = hv * asl[c2];
    float gpd = hv * adl[c2];
#pragma unroll
    for (int d2 = 32; d2 >= 1; d2 >>= 1) { gps += __shfl_xor(gps, d2); gpd += __shfl_xor(gpd, d2); }
    if (lane == 0) { int h2 = wid & 3; asT[h2 * 128 + r2] = gps; adT[h2 * 128 + r2] = gpd; }
    *(unsigned short*)(Ht + ((c2 * 256 + r2 * 2) ^ SW(c2))) = f2bf(hv);
  }
  __syncthreads();                                 // b1: scatter/hT/asT/adT complete

  // ---- compact M int -> bf16 in place ----
  {
    const int crow = tid >> 3, cs = (tid & 7) * 16;
    uint4 cv[4];
#pragma unroll
    for (int j = 0; j < 4; ++j)
      cv[j] = *(const uint4*)(Mb + ((crow * 512 + cs * 4 + j * 16) ^ SW(crow)));
    __syncthreads();                               // b2: all reads done
    const int* ip = (const int*)cv;
    uint4 o0, o1;
    o0.x = (unsigned)f2bf((float)ip[0])  | ((unsigned)f2bf((float)ip[1])  << 16);
    o0.y = (unsigned)f2bf((float)ip[2])  | ((unsigned)f2bf((float)ip[3])  << 16);
    o0.z = (unsigned)f2bf((float)ip[4])  | ((unsigned)f2bf((float)ip[5])  << 16);
    o0.w = (unsigned)f2bf((float)ip[6])  | ((unsigned)f2bf((float)ip[7])  << 16);
    o1.x = (unsigned)f2bf((float)ip[8])  | ((unsigned)f2bf((float)ip[9])  << 16);
    o1.y = (unsigned)f2bf((float)ip[10]) | ((unsigned)f2bf((float)ip[11]) << 16);
    o1.z = (unsigned)f2bf((float)ip[12]) | ((unsigned)f2bf((float)ip[13]) << 16);
    o1.w = (unsigned)f2bf((float)ip[14]) | ((unsigned)f2bf((float)ip[15]) << 16);
    *(uint4*)(Mb + ((crow * 256 + cs * 2) ^ SW(crow)))      = o0;
    *(uint4*)(Mb + ((crow * 256 + cs * 2 + 16) ^ SW(crow))) = o1;
  }
  __syncthreads();                                 // b3: M bf16 ready

  // ---- 4 head passes, BARRIER-FREE: A built in-register from M, as, ad ----
  float lp[4] = {};
  const int m2 = (wid & 7) * 16, n2 = (wid >> 3) * 32;

  for (int hd = 0; hd < 4; ++hd) {
    const float adv = adT[hd * 128 + m2 + rl];
    float denp = 0.f;
    f32x4 acc2[2] = {};
#pragma unroll
    for (int ks = 0; ks < 4; ++ks) {
      const int row = m2 + rl;
      bf16x8 m8 = *(const bf16x8*)(Mb + ((row * 256 + (ks * 32 + kg * 8) * 2) ^ SW(row)));
      f32x4 as0 = *(const f32x4*)(&asT[hd * 128 + ks * 32 + kg * 8]);
      f32x4 as1 = *(const f32x4*)(&asT[hd * 128 + ks * 32 + kg * 8 + 4]);
      float av[8];
#pragma unroll
      for (int j = 0; j < 8; ++j) {
        float e = ((j < 4) ? as0[j] : as1[j - 4]) + adv;
        e = (e < 0.f) ? NEG_SLOPE * e : e;
        float w = __expf(e);
        float mval = bf2f((unsigned short)m8[j]);
        av[j] = mval * w;
        denp += av[j];
      }
      bf16x8 a2;
#pragma unroll
      for (int j = 0; j < 8; ++j) a2[j] = (short)f2bf(av[j]);
      bf16x8 b2[2];
#pragma unroll
      for (int nf = 0; nf < 2; ++nf) {
        int dim = hd * 64 + n2 + nf * 16 + rl;
        b2[nf] = *(const bf16x8*)(Ht + ((dim * 256 + (ks * 32 + kg * 8) * 2) ^ SW(dim)));
      }
#pragma unroll
      for (int nf = 0; nf < 2; ++nf)
        acc2[nf] = __builtin_amdgcn_mfma_f32_16x16x32_bf16(a2, b2[nf], acc2[nf], 0, 0, 0);
    }
    // den[m2+rl] per lane (sum the 4 kg slices)
    denp += __shfl_xor(denp, 16);
    denp += __shfl_xor(denp, 32);
    // epilogue: normalize + ELU + readout accumulate
#pragma unroll
    for (int i = 0; i < 4; ++i) {
      float dni = __shfl(denp, kg * 4 + i);        // lane kg*4+i holds rl == kg*4+i
      float rd = __builtin_amdgcn_rcpf(dni + 1e-16f);
#pragma unroll
      for (int nf = 0; nf < 2; ++nf) {
        float v = acc2[nf][i] * rd;
        v = (v > 0.f) ? v : (__expf(v) - 1.f);
        lp[i] += v * wo[hd * 64 + n2 + nf * 16 + rl];
      }
    }
  }

  // ---- final readout reduce ----
#pragma unroll
  for (int i = 0; i < 4; ++i) {
    float v = lp[i];
#pragma unroll
    for (int d2 = 1; d2 < 16; d2 <<= 1) v += __shfl_xor(v, d2);
    if (rl == 0) lpf[(m2 + kg * 4 + i) * 2 + (wid >> 3)] = v;
  }
  __syncthreads();                                 // b4
  if (tid < F_) out[(size_t)g * F_ + tid] = lpf[tid * 2] + lpf[tid * 2 + 1] + bo;
}

extern "C" void kernel_launch(void* const* d_in, const int* in_sizes, int n_in,
                              void* d_out, int out_size, void* d_ws, size_t ws_size,
                              hipStream_t stream) {
  const int* fid      = (const int*)d_in[0];
  const int* userid   = (const int*)d_in[1];
  const int* itemid   = (const int*)d_in[2];
  const int* ei       = (const int*)d_in[3];
  const float* ftab   = (const float*)d_in[4];
  const float* utab   = (const float*)d_in[5];
  const float* itab   = (const float*)d_in[6];
  const float* Wf     = (const float*)d_in[7];
  const float* Wu     = (const float*)d_in[8];
  const float* Wi     = (const float*)d_in[9];
  const float* Wg     = (const float*)d_in[10];
  const float* a_src  = (const float*)d_in[11];
  const float* a_dst  = (const float*)d_in[12];
  const float* W_out  = (const float*)d_in[13];
  const float* b_out  = (const float*)d_in[14];
  float* out = (float*)d_out;

  unsigned short* ws_wct = (unsigned short*)d_ws;   // 384 KB

  hipLaunchKernelGGL(k0_wct, dim3(96), dim3(256), 0, stream, Wf, Wu, Wi, Wg, ws_wct);
  hipLaunchKernelGGL(k2f, dim3(256), dim3(1024), 0, stream,
                     fid, userid, itemid, ei, ftab, utab, itab, ws_wct,
                     a_src, a_dst, W_out, b_out, out);
}